// Round 7
// baseline (300.364 us; speedup 1.0000x reference)
//
#include <hip/hip_runtime.h>
#include <hip/hip_fp16.h>
#include <math.h>

#define DEMB 128
#define DHID 64
#define DOUT 32
#define BAG  10
#define CAP  64      // padded adjacency capacity per node (Poisson(16), P(>64)~1e-20)
#define SUB  8       // sub-streams per bucket (XCD affinity via blockIdx&7)
#define SUBCAP 768   // capacity per (bucket,sub): mean 512, 11 sigma headroom

typedef unsigned int   u32;
typedef unsigned short u16;

__device__ __forceinline__ float bf2f(u16 u) {
    union { u32 i; float f; } c; c.i = (u32)u << 16; return c.f;
}
__device__ __forceinline__ u16 f2bf(float f) {
    union { float f; u32 i; } c; c.f = f;
    u32 r = c.i + 0x7FFFu + ((c.i >> 16) & 1u);
    return (u16)(r >> 16);
}
__device__ __forceinline__ void bf2x(u32 v, float& lo, float& hi) {
    union { u32 i; float f; } a, b;
    a.i = v << 16; b.i = v & 0xFFFF0000u;
    lo = a.f; hi = b.f;
}
__device__ __forceinline__ u32 pack2(float f0, float f1) {
    return (u32)f2bf(f0) | ((u32)f2bf(f1) << 16);
}
__device__ __forceinline__ float2 h2f2(u32 v) {
    __half2 h; *reinterpret_cast<u32*>(&h) = v;
    return __half22float2(h);
}
__device__ __forceinline__ u32 f2h2(float a, float b) {
    __half2 h = __floats2half2_rn(a, b);
    return *reinterpret_cast<u32*>(&h);
}

// ---------------------------------------------------------------------------
// fusedA: co-dispatch of
//   (a) phase-1 edge bucketing: bucket = dst>>8, entry = src | (dst&255)<<24
//       written to per-(bucket, blockIdx&7) stream -> L2-coalescing tail writes
//   (b) gemm_table: tableW[v] = emb_table[v] @ W1, bf16
__global__ __launch_bounds__(256) void fusedA(const int* __restrict__ src,
                                              const int* __restrict__ dst, int E,
                                              int* __restrict__ cur, u32* __restrict__ bbuf,
                                              const float* __restrict__ T,
                                              const float* __restrict__ W1,
                                              u16* __restrict__ TW, int V) {
    const int b = blockIdx.x;
    const int nbb = (E + 255) >> 8;            // bucket-scatter blocks
    const int grp = b / 3, rem = b - grp * 3;
    const bool is_build = (rem == 2) && (grp < nbb);
    if (is_build) {
        int e = grp * 256 + threadIdx.x;
        if (e < E) {
            int d = dst[e];
            int s = src[e];
            int bkt = d >> 8;
            int sub = b & 7;
            int slot = atomicAdd(&cur[bkt * SUB + sub], 1);
            if (slot < SUBCAP)
                bbuf[((size_t)bkt * SUB + sub) * SUBCAP + slot] =
                    (u32)s | ((u32)(d & 255) << 24);
        }
        return;
    }
    // gemm_table block
    __shared__ float Ws[DEMB * DHID];          // 32 KiB
    int before = grp < nbb ? grp : nbb;        // build blocks with index < b
    int gb = b - before;
    const int nbg = (V + 3) >> 2;
    if (gb >= nbg) return;
    for (int i = threadIdx.x; i < DEMB * DHID; i += 256) Ws[i] = W1[i];
    __syncthreads();
    int row = gb * 4 + (threadIdx.x >> 6);
    int col = threadIdx.x & 63;
    if (row >= V) return;
    const float* trow = T + (size_t)row * DEMB;
    float acc = 0.f;
#pragma unroll 8
    for (int k = 0; k < DEMB; ++k) acc = fmaf(trow[k], Ws[k * DHID + col], acc);
    TW[(size_t)row * DHID + col] = f2bf(acc);
}

// ---------------------------------------------------------------------------
// phase-2: one block per bucket (256 nodes). Build padded adjacency in LDS
// (LDS atomics + LDS writes), then dump coalesced; emit degc.
__global__ __launch_bounds__(256) void adj_build(const u32* __restrict__ bbuf,
                                                 const int* __restrict__ cur,
                                                 int* __restrict__ adj,
                                                 int* __restrict__ degc,
                                                 int n, int nbkt) {
    __shared__ int cnt[256];
    __shared__ __align__(16) int adjS[256 * CAP];   // 64 KiB
    const int b = blockIdx.x;
    cnt[threadIdx.x] = 0;
    __syncthreads();
#pragma unroll
    for (int x = 0; x < SUB; ++x) {
        int m = cur[b * SUB + x];
        if (m > SUBCAP) m = SUBCAP;
        const u32* p = bbuf + ((size_t)b * SUB + x) * SUBCAP;
        for (int i = threadIdx.x; i < m; i += 256) {
            u32 v = p[i];
            int dl = v >> 24;
            int r = atomicAdd(&cnt[dl], 1);
            if (r < CAP) adjS[dl * CAP + r] = (int)(v & 0x00FFFFFFu);
        }
    }
    __syncthreads();
    const int base = b * 256;
    int nn = n - base; if (nn > 256) nn = 256;
    if ((int)threadIdx.x < nn) degc[base + threadIdx.x] = cnt[threadIdx.x];
    // coalesced dump: nn rows x CAP ints = nn*16 int4s
    int tot4 = nn * 16;
    int4* gout = reinterpret_cast<int4*>(adj + (size_t)base * CAP);
    const int4* lin = reinterpret_cast<const int4*>(adjS);
    for (int i = threadIdx.x; i < tot4; i += 256) gout[i] = lin[i];
}

// ---------------------------------------------------------------------------
// h0s[n] = dinv[n] * mean_j tableW[idx[n*BAG+j]]   (bf16 in/out, pre-scaled)
__global__ void emb_bag(const int* __restrict__ idx, const u16* __restrict__ TW,
                        const int* __restrict__ degc, u16* __restrict__ h0, int n) {
    int t = blockIdx.x * blockDim.x + threadIdx.x;
    int node = t >> 3, d8 = t & 7;
    if (node >= n) return;
    const int* bi = idx + (size_t)node * BAG;
    float a[8] = {0.f, 0.f, 0.f, 0.f, 0.f, 0.f, 0.f, 0.f};
#pragma unroll
    for (int j = 0; j < BAG; ++j) {
        uint4 v = *reinterpret_cast<const uint4*>(TW + (size_t)bi[j] * DHID + d8 * 8);
        float f0, f1; bf2x(v.x, f0, f1); a[0] += f0; a[1] += f1;
        bf2x(v.y, f0, f1); a[2] += f0; a[3] += f1;
        bf2x(v.z, f0, f1); a[4] += f0; a[5] += f1;
        bf2x(v.w, f0, f1); a[6] += f0; a[7] += f1;
    }
    float s = rsqrtf((float)(degc[node] + 1)) * (1.0f / (float)BAG);
    uint4 o;
    o.x = pack2(a[0] * s, a[1] * s);
    o.y = pack2(a[2] * s, a[3] * s);
    o.z = pack2(a[4] * s, a[5] * s);
    o.w = pack2(a[6] * s, a[7] * s);
    *reinterpret_cast<uint4*>(h0 + (size_t)node * DHID + d8 * 8) = o;
}

// ---------------------------------------------------------------------------
__device__ __forceinline__ void acc_row(const u16* __restrict__ base, float* a) {
    uint4 v = *reinterpret_cast<const uint4*>(base);
    float f0, f1; bf2x(v.x, f0, f1); a[0] += f0; a[1] += f1;
    bf2x(v.y, f0, f1); a[2] += f0; a[3] += f1;
    bf2x(v.z, f0, f1); a[4] += f0; a[5] += f1;
    bf2x(v.w, f0, f1); a[6] += f0; a[7] += f1;
}

// ---------------------------------------------------------------------------
// conv1mm: fused gather-conv1 (relu) + gemm_h, via LDS staging.
#define HPAD 68
__global__ __launch_bounds__(256) void conv1mm(const u16* __restrict__ h0,
                                               const int* __restrict__ degc,
                                               const int* __restrict__ adj,
                                               const float* __restrict__ b1,
                                               const float* __restrict__ Wmu,
                                               const float* __restrict__ Wls,
                                               u16* __restrict__ hcat, int n) {
    __shared__ u16   Wp[DHID * DHID];   // 8 KiB, bf16, permuted [k][p]
    __shared__ float hs[32][HPAD];      // staging
    for (int i = threadIdx.x; i < DHID * DHID; i += 256) {
        int k = i >> 6, p = i & 63;
        int j = p >> 3, c = p & 7;
        float w = (c < 4) ? Wmu[k * DOUT + j * 4 + c] : Wls[k * DOUT + j * 4 + (c - 4)];
        Wp[i] = f2bf(w);
    }
    int t = blockIdx.x * 256 + threadIdx.x;
    int node = t >> 3, d8 = t & 7;
    int lnode = threadIdx.x >> 3;
    int dc = 0;
    if (node < n) {
        dc = degc[node];
        int deg = dc < CAP ? dc : CAP;
        const int* ap = adj + (size_t)node * CAP;
        float a[8] = {0.f, 0.f, 0.f, 0.f, 0.f, 0.f, 0.f, 0.f};
        acc_row(h0 + (size_t)node * DHID + d8 * 8, a);   // self loop
        int k = 0;
        for (; k + 4 <= deg; k += 4) {
            int4 ss = *reinterpret_cast<const int4*>(ap + k);
            acc_row(h0 + (size_t)ss.x * DHID + d8 * 8, a);
            acc_row(h0 + (size_t)ss.y * DHID + d8 * 8, a);
            acc_row(h0 + (size_t)ss.z * DHID + d8 * 8, a);
            acc_row(h0 + (size_t)ss.w * DHID + d8 * 8, a);
        }
        for (; k < deg; ++k) acc_row(h0 + (size_t)ap[k] * DHID + d8 * 8, a);

        float di = rsqrtf((float)(dc + 1));
        float4 b0 = *reinterpret_cast<const float4*>(b1 + d8 * 8);
        float4 b4 = *reinterpret_cast<const float4*>(b1 + d8 * 8 + 4);
        float4 o0, o1;
        o0.x = fmaxf(fmaf(di, a[0], b0.x), 0.f);
        o0.y = fmaxf(fmaf(di, a[1], b0.y), 0.f);
        o0.z = fmaxf(fmaf(di, a[2], b0.z), 0.f);
        o0.w = fmaxf(fmaf(di, a[3], b0.w), 0.f);
        o1.x = fmaxf(fmaf(di, a[4], b4.x), 0.f);
        o1.y = fmaxf(fmaf(di, a[5], b4.y), 0.f);
        o1.z = fmaxf(fmaf(di, a[6], b4.z), 0.f);
        o1.w = fmaxf(fmaf(di, a[7], b4.w), 0.f);
        *reinterpret_cast<float4*>(&hs[lnode][d8 * 8])     = o0;
        *reinterpret_cast<float4*>(&hs[lnode][d8 * 8 + 4]) = o1;
    }
    __syncthreads();
    if (node >= n) return;
    float acc[8] = {0.f, 0.f, 0.f, 0.f, 0.f, 0.f, 0.f, 0.f};
#pragma unroll 4
    for (int k = 0; k < DHID; ++k) {
        float hv = hs[lnode][k];
        uint4 wv = *reinterpret_cast<const uint4*>(&Wp[k * DHID + d8 * 8]);
        float f0, f1;
        bf2x(wv.x, f0, f1); acc[0] = fmaf(hv, f0, acc[0]); acc[1] = fmaf(hv, f1, acc[1]);
        bf2x(wv.y, f0, f1); acc[2] = fmaf(hv, f0, acc[2]); acc[3] = fmaf(hv, f1, acc[3]);
        bf2x(wv.z, f0, f1); acc[4] = fmaf(hv, f0, acc[4]); acc[5] = fmaf(hv, f1, acc[5]);
        bf2x(wv.w, f0, f1); acc[6] = fmaf(hv, f0, acc[6]); acc[7] = fmaf(hv, f1, acc[7]);
    }
    float di = rsqrtf((float)(dc + 1));
    uint4 o;
    o.x = pack2(acc[0] * di, acc[1] * di);
    o.y = pack2(acc[2] * di, acc[3] * di);
    o.z = pack2(acc[4] * di, acc[5] * di);
    o.w = pack2(acc[6] * di, acc[7] * di);
    *reinterpret_cast<uint4*>(hcat + (size_t)node * DHID + d8 * 8) = o;
}

// ---------------------------------------------------------------------------
// conv2 + reparameterize. hcat interleaved: ONE uint4 per neighbor-lane.
__device__ __forceinline__ void acc_row2i(const u16* __restrict__ row, int j,
                                          float* am, float* al) {
    uint4 v = *reinterpret_cast<const uint4*>(row + j * 8);
    float f0, f1;
    bf2x(v.x, f0, f1); am[0] += f0; am[1] += f1;
    bf2x(v.y, f0, f1); am[2] += f0; am[3] += f1;
    bf2x(v.z, f0, f1); al[0] += f0; al[1] += f1;
    bf2x(v.w, f0, f1); al[2] += f0; al[3] += f1;
}

__global__ void gather_conv2(const u16* __restrict__ hcat, const int* __restrict__ degc,
                             const int* __restrict__ adj,
                             const float* __restrict__ bmu, const float* __restrict__ bls,
                             const float* __restrict__ noise, __half* __restrict__ z, int n) {
    int t = blockIdx.x * blockDim.x + threadIdx.x;
    int node = t >> 3, j = t & 7;
    if (node >= n) return;
    int dc = degc[node];
    int deg = dc < CAP ? dc : CAP;
    const int* ap = adj + (size_t)node * CAP;
    float am[4] = {0.f, 0.f, 0.f, 0.f};
    float al[4] = {0.f, 0.f, 0.f, 0.f};
    acc_row2i(hcat + (size_t)node * DHID, j, am, al);   // self loop
    int k = 0;
    for (; k + 4 <= deg; k += 4) {
        int4 ss = *reinterpret_cast<const int4*>(ap + k);
        acc_row2i(hcat + (size_t)ss.x * DHID, j, am, al);
        acc_row2i(hcat + (size_t)ss.y * DHID, j, am, al);
        acc_row2i(hcat + (size_t)ss.z * DHID, j, am, al);
        acc_row2i(hcat + (size_t)ss.w * DHID, j, am, al);
    }
    for (; k < deg; ++k) acc_row2i(hcat + (size_t)ap[k] * DHID, j, am, al);

    float di = rsqrtf((float)(dc + 1));
    float4 bm = *reinterpret_cast<const float4*>(bmu + j * 4);
    float4 bl = *reinterpret_cast<const float4*>(bls + j * 4);
    float4 nz = *reinterpret_cast<const float4*>(noise + (size_t)node * DOUT + j * 4);
    float z0 = fmaf(di, am[0], bm.x) + nz.x * expf(fmaf(di, al[0], bl.x));
    float z1 = fmaf(di, am[1], bm.y) + nz.y * expf(fmaf(di, al[1], bl.y));
    float z2 = fmaf(di, am[2], bm.z) + nz.z * expf(fmaf(di, al[2], bl.z));
    float z3 = fmaf(di, am[3], bm.w) + nz.w * expf(fmaf(di, al[3], bl.w));
    uint2 o;
    o.x = f2h2(z0, z1);
    o.y = f2h2(z2, z3);
    *reinterpret_cast<uint2*>(z + (size_t)node * DOUT + j * 4) = o;
}

// ---------------------------------------------------------------------------
// out[e] = sigmoid(dot(z[src[e]], z[dst[e]])), 4 lanes/edge (8 fp16 each)
__global__ void edge_dot(const __half* __restrict__ z, const int* __restrict__ src,
                         const int* __restrict__ dst, float* __restrict__ out, int E) {
    int t = blockIdx.x * blockDim.x + threadIdx.x;
    int e = t >> 2, q = t & 3;
    if (e >= E) return;
    uint4 a = *reinterpret_cast<const uint4*>(z + (size_t)src[e] * DOUT + q * 8);
    uint4 b = *reinterpret_cast<const uint4*>(z + (size_t)dst[e] * DOUT + q * 8);
    float s = 0.f;
    float2 x, y;
    x = h2f2(a.x); y = h2f2(b.x); s += x.x * y.x + x.y * y.y;
    x = h2f2(a.y); y = h2f2(b.y); s += x.x * y.x + x.y * y.y;
    x = h2f2(a.z); y = h2f2(b.z); s += x.x * y.x + x.y * y.y;
    x = h2f2(a.w); y = h2f2(b.w); s += x.x * y.x + x.y * y.y;
    s += __shfl_xor(s, 1);
    s += __shfl_xor(s, 2);
    if (q == 0) out[e] = 1.0f / (1.0f + expf(-s));
}

// ---------------------------------------------------------------------------
extern "C" void kernel_launch(void* const* d_in, const int* in_sizes, int n_in,
                              void* d_out, int out_size, void* d_ws, size_t ws_size,
                              hipStream_t stream) {
    const int*   feat_idx = (const int*)d_in[0];
    const int*   edges    = (const int*)d_in[2];
    const float* table    = (const float*)d_in[3];
    const float* W1       = (const float*)d_in[4];
    const float* b1       = (const float*)d_in[5];
    const float* Wmu      = (const float*)d_in[6];
    const float* bmu      = (const float*)d_in[7];
    const float* Wls      = (const float*)d_in[8];
    const float* bls      = (const float*)d_in[9];
    const float* noise    = (const float*)d_in[10];

    const int N = in_sizes[10] / DOUT;
    const int E = in_sizes[2] / 2;
    const int V = in_sizes[3] / DEMB;
    const int NBKT = (N + 255) >> 8;

    const int* src = edges;
    const int* dst = edges + E;

    // --- workspace partition ---
    char* ws = (char*)d_ws;
    size_t off = 0;
    auto alloc = [&](size_t bytes) { char* p = ws + off; off += (bytes + 255) & ~size_t(255); return p; };
    u16*    tableW = (u16*)   alloc((size_t)V * DHID * 2);             //  6.4 MB
    u16*    h0     = (u16*)   alloc((size_t)N * DHID * 2);             // 12.8 MB
    u16*    hcat   = (u16*)   alloc((size_t)N * DHID * 2);             // 12.8 MB
    __half* zbuf   = (__half*)alloc((size_t)N * DOUT * 2);             //  6.4 MB
    int*    adj    = (int*)   alloc((size_t)N * CAP * 4);              // 25.6 MB
    int*    degc   = (int*)   alloc((size_t)NBKT * 256 * 4);           //  0.4 MB
    u32*    bbuf   = (u32*)   alloc((size_t)NBKT * SUB * SUBCAP * 4);  //  9.6 MB
    int*    cur    = (int*)   alloc((size_t)NBKT * SUB * 4);           // 12.5 KB
    (void)ws_size;

    hipMemsetAsync(cur, 0, (size_t)NBKT * SUB * 4, stream);

    const int B = 256;
    const int nb_build = (E + B - 1) / B;
    const int nb_gemm  = (V + 3) / 4;

    // phase-1 edge bucketing ∥ table GEMM (co-dispatched)
    fusedA<<<nb_build + nb_gemm, B, 0, stream>>>(src, dst, E, cur, bbuf,
                                                 table, W1, tableW, V);

    // phase-2: LDS-local adjacency build + coalesced dump
    adj_build<<<NBKT, B, 0, stream>>>(bbuf, cur, adj, degc, N, NBKT);

    // h0s = dinv * embedding_bag_mean(tableW, idx)
    {
        long long t = (long long)N * 8;
        emb_bag<<<(unsigned)((t + B - 1) / B), B, 0, stream>>>(feat_idx, tableW, degc, h0, N);
    }

    // conv1 (gather, relu) + gemm_h fused -> interleaved bf16 hcat
    conv1mm<<<(N + 31) / 32, B, 0, stream>>>(h0, degc, adj, b1, Wmu, Wls, hcat, N);

    // conv2 (gather, fused reparameterize) -> fp16 z
    {
        long long t = (long long)N * 8;
        gather_conv2<<<(unsigned)((t + B - 1) / B), B, 0, stream>>>(hcat, degc, adj,
                                                                    bmu, bls, noise, zbuf, N);
    }

    // decoder
    {
        long long t = (long long)E * 4;
        edge_dot<<<(unsigned)((t + B - 1) / B), B, 0, stream>>>(zbuf, src, dst, (float*)d_out, E);
    }
}

// Round 8
// 243.186 us; speedup vs baseline: 1.2351x; 1.2351x over previous
//
#include <hip/hip_runtime.h>
#include <hip/hip_fp16.h>
#include <math.h>

#define DEMB 128
#define DHID 64
#define DOUT 32
#define BAG  10
#define CAP  64     // padded adjacency capacity per node (Poisson(16), P(>64)~1e-20)

typedef unsigned int   u32;
typedef unsigned short u16;

__device__ __forceinline__ float bf2f(u16 u) {
    union { u32 i; float f; } c; c.i = (u32)u << 16; return c.f;
}
__device__ __forceinline__ u16 f2bf(float f) {
    union { float f; u32 i; } c; c.f = f;
    u32 r = c.i + 0x7FFFu + ((c.i >> 16) & 1u);
    return (u16)(r >> 16);
}
__device__ __forceinline__ void bf2x(u32 v, float& lo, float& hi) {
    union { u32 i; float f; } a, b;
    a.i = v << 16; b.i = v & 0xFFFF0000u;
    lo = a.f; hi = b.f;
}
__device__ __forceinline__ u32 pack2(float f0, float f1) {
    return (u32)f2bf(f0) | ((u32)f2bf(f1) << 16);
}
__device__ __forceinline__ float2 h2f2(u32 v) {
    __half2 h; *reinterpret_cast<u32*>(&h) = v;
    return __half22float2(h);
}
__device__ __forceinline__ u32 f2h2(float a, float b) {
    __half2 h = __floats2half2_rn(a, b);
    return *reinterpret_cast<u32*>(&h);
}

// ---------------------------------------------------------------------------
// fusedA: co-dispatch (NO LDS anywhere -> high occupancy for the build blocks)
//   role rem==0 : build_adj  r = degc[dst]++ ; adj[dst*CAP+r] = src
//   role rem!=0 : gemm_table tableW[row] = emb_table[row] @ W1 (one row/wave,
//                 row uniform per wave -> broadcast loads; W1 read coalesced/L2)
__global__ __launch_bounds__(256) void fusedA(const int* __restrict__ src,
                                              const int* __restrict__ dst, int E,
                                              int* __restrict__ degc, int* __restrict__ adj,
                                              const float* __restrict__ T,
                                              const float* __restrict__ W1,
                                              u16* __restrict__ TW, int V) {
    const int b = blockIdx.x;
    const int grp = b / 3, rem = b - grp * 3;
    const int nbb = (E + 255) >> 8;
    if (rem == 0) {
        if (grp < nbb) {
            int e = grp * 256 + threadIdx.x;
            if (e < E) {
                int d = dst[e];
                int r = atomicAdd(&degc[d], 1);
                if (r < CAP) adj[(size_t)d * CAP + r] = src[e];
            }
        }
        return;
    }
    int gb = grp * 2 + (rem - 1);          // gemm block id
    int row = gb * 4 + (threadIdx.x >> 6); // one row per wave
    int col = threadIdx.x & 63;
    if (row >= V) return;
    const float* trow = T + (size_t)row * DEMB;
    float acc = 0.f;
#pragma unroll 8
    for (int k = 0; k < DEMB; ++k) acc = fmaf(trow[k], W1[k * DHID + col], acc);
    TW[(size_t)row * DHID + col] = f2bf(acc);
}

// ---------------------------------------------------------------------------
// h0s[n] = dinv[n] * mean_j tableW[idx[n*BAG+j]]   (bf16 in/out, pre-scaled)
__global__ void emb_bag(const int* __restrict__ idx, const u16* __restrict__ TW,
                        const int* __restrict__ degc, u16* __restrict__ h0, int n) {
    int t = blockIdx.x * blockDim.x + threadIdx.x;
    int node = t >> 3, d8 = t & 7;
    if (node >= n) return;
    const int* bi = idx + (size_t)node * BAG;
    float a[8] = {0.f, 0.f, 0.f, 0.f, 0.f, 0.f, 0.f, 0.f};
#pragma unroll
    for (int j = 0; j < BAG; ++j) {
        uint4 v = *reinterpret_cast<const uint4*>(TW + (size_t)bi[j] * DHID + d8 * 8);
        float f0, f1; bf2x(v.x, f0, f1); a[0] += f0; a[1] += f1;
        bf2x(v.y, f0, f1); a[2] += f0; a[3] += f1;
        bf2x(v.z, f0, f1); a[4] += f0; a[5] += f1;
        bf2x(v.w, f0, f1); a[6] += f0; a[7] += f1;
    }
    float s = rsqrtf((float)(degc[node] + 1)) * (1.0f / (float)BAG);
    uint4 o;
    o.x = pack2(a[0] * s, a[1] * s);
    o.y = pack2(a[2] * s, a[3] * s);
    o.z = pack2(a[4] * s, a[5] * s);
    o.w = pack2(a[6] * s, a[7] * s);
    *reinterpret_cast<uint4*>(h0 + (size_t)node * DHID + d8 * 8) = o;
}

// ---------------------------------------------------------------------------
__device__ __forceinline__ void acc_row(const u16* __restrict__ base, float* a) {
    uint4 v = *reinterpret_cast<const uint4*>(base);
    float f0, f1; bf2x(v.x, f0, f1); a[0] += f0; a[1] += f1;
    bf2x(v.y, f0, f1); a[2] += f0; a[3] += f1;
    bf2x(v.z, f0, f1); a[4] += f0; a[5] += f1;
    bf2x(v.w, f0, f1); a[6] += f0; a[7] += f1;
}

// ---------------------------------------------------------------------------
// conv1mm: fused gather-conv1 (relu) + gemm_h, via LDS staging.
// Phase 2 writes hcat in INTERLEAVED layout: slot p=j*8+c: c<4 -> mu[j*4+c],
// c>=4 -> ls[j*4+(c-4)], pre-scaled by dinv[node].
#define HPAD 68
__global__ __launch_bounds__(256) void conv1mm(const u16* __restrict__ h0,
                                               const int* __restrict__ degc,
                                               const int* __restrict__ adj,
                                               const float* __restrict__ b1,
                                               const float* __restrict__ Wmu,
                                               const float* __restrict__ Wls,
                                               u16* __restrict__ hcat, int n) {
    __shared__ u16   Wp[DHID * DHID];   // 8 KiB, bf16, permuted [k][p]
    __shared__ float hs[32][HPAD];      // staging
    for (int i = threadIdx.x; i < DHID * DHID; i += 256) {
        int k = i >> 6, p = i & 63;
        int j = p >> 3, c = p & 7;
        float w = (c < 4) ? Wmu[k * DOUT + j * 4 + c] : Wls[k * DOUT + j * 4 + (c - 4)];
        Wp[i] = f2bf(w);
    }
    int t = blockIdx.x * 256 + threadIdx.x;
    int node = t >> 3, d8 = t & 7;
    int lnode = threadIdx.x >> 3;
    int dc = 0;
    if (node < n) {
        dc = degc[node];
        int deg = dc < CAP ? dc : CAP;
        const int* ap = adj + (size_t)node * CAP;
        float a[8] = {0.f, 0.f, 0.f, 0.f, 0.f, 0.f, 0.f, 0.f};
        acc_row(h0 + (size_t)node * DHID + d8 * 8, a);   // self loop
        int k = 0;
        for (; k + 4 <= deg; k += 4) {
            int4 ss = *reinterpret_cast<const int4*>(ap + k);
            acc_row(h0 + (size_t)ss.x * DHID + d8 * 8, a);
            acc_row(h0 + (size_t)ss.y * DHID + d8 * 8, a);
            acc_row(h0 + (size_t)ss.z * DHID + d8 * 8, a);
            acc_row(h0 + (size_t)ss.w * DHID + d8 * 8, a);
        }
        for (; k < deg; ++k) acc_row(h0 + (size_t)ap[k] * DHID + d8 * 8, a);

        float di = rsqrtf((float)(dc + 1));
        float4 b0 = *reinterpret_cast<const float4*>(b1 + d8 * 8);
        float4 b4 = *reinterpret_cast<const float4*>(b1 + d8 * 8 + 4);
        float4 o0, o1;
        o0.x = fmaxf(fmaf(di, a[0], b0.x), 0.f);
        o0.y = fmaxf(fmaf(di, a[1], b0.y), 0.f);
        o0.z = fmaxf(fmaf(di, a[2], b0.z), 0.f);
        o0.w = fmaxf(fmaf(di, a[3], b0.w), 0.f);
        o1.x = fmaxf(fmaf(di, a[4], b4.x), 0.f);
        o1.y = fmaxf(fmaf(di, a[5], b4.y), 0.f);
        o1.z = fmaxf(fmaf(di, a[6], b4.z), 0.f);
        o1.w = fmaxf(fmaf(di, a[7], b4.w), 0.f);
        *reinterpret_cast<float4*>(&hs[lnode][d8 * 8])     = o0;
        *reinterpret_cast<float4*>(&hs[lnode][d8 * 8 + 4]) = o1;
    }
    __syncthreads();
    if (node >= n) return;
    float acc[8] = {0.f, 0.f, 0.f, 0.f, 0.f, 0.f, 0.f, 0.f};
#pragma unroll 4
    for (int k = 0; k < DHID; ++k) {
        float hv = hs[lnode][k];
        uint4 wv = *reinterpret_cast<const uint4*>(&Wp[k * DHID + d8 * 8]);
        float f0, f1;
        bf2x(wv.x, f0, f1); acc[0] = fmaf(hv, f0, acc[0]); acc[1] = fmaf(hv, f1, acc[1]);
        bf2x(wv.y, f0, f1); acc[2] = fmaf(hv, f0, acc[2]); acc[3] = fmaf(hv, f1, acc[3]);
        bf2x(wv.z, f0, f1); acc[4] = fmaf(hv, f0, acc[4]); acc[5] = fmaf(hv, f1, acc[5]);
        bf2x(wv.w, f0, f1); acc[6] = fmaf(hv, f0, acc[6]); acc[7] = fmaf(hv, f1, acc[7]);
    }
    float di = rsqrtf((float)(dc + 1));
    uint4 o;
    o.x = pack2(acc[0] * di, acc[1] * di);
    o.y = pack2(acc[2] * di, acc[3] * di);
    o.z = pack2(acc[4] * di, acc[5] * di);
    o.w = pack2(acc[6] * di, acc[7] * di);
    *reinterpret_cast<uint4*>(hcat + (size_t)node * DHID + d8 * 8) = o;
}

// ---------------------------------------------------------------------------
// conv2 + reparameterize. hcat interleaved: ONE uint4 per neighbor-lane.
__device__ __forceinline__ void acc_row2i(const u16* __restrict__ row, int j,
                                          float* am, float* al) {
    uint4 v = *reinterpret_cast<const uint4*>(row + j * 8);
    float f0, f1;
    bf2x(v.x, f0, f1); am[0] += f0; am[1] += f1;
    bf2x(v.y, f0, f1); am[2] += f0; am[3] += f1;
    bf2x(v.z, f0, f1); al[0] += f0; al[1] += f1;
    bf2x(v.w, f0, f1); al[2] += f0; al[3] += f1;
}

__global__ void gather_conv2(const u16* __restrict__ hcat, const int* __restrict__ degc,
                             const int* __restrict__ adj,
                             const float* __restrict__ bmu, const float* __restrict__ bls,
                             const float* __restrict__ noise, __half* __restrict__ z, int n) {
    int t = blockIdx.x * blockDim.x + threadIdx.x;
    int node = t >> 3, j = t & 7;
    if (node >= n) return;
    int dc = degc[node];
    int deg = dc < CAP ? dc : CAP;
    const int* ap = adj + (size_t)node * CAP;
    float am[4] = {0.f, 0.f, 0.f, 0.f};
    float al[4] = {0.f, 0.f, 0.f, 0.f};
    acc_row2i(hcat + (size_t)node * DHID, j, am, al);   // self loop
    int k = 0;
    for (; k + 4 <= deg; k += 4) {
        int4 ss = *reinterpret_cast<const int4*>(ap + k);
        acc_row2i(hcat + (size_t)ss.x * DHID, j, am, al);
        acc_row2i(hcat + (size_t)ss.y * DHID, j, am, al);
        acc_row2i(hcat + (size_t)ss.z * DHID, j, am, al);
        acc_row2i(hcat + (size_t)ss.w * DHID, j, am, al);
    }
    for (; k < deg; ++k) acc_row2i(hcat + (size_t)ap[k] * DHID, j, am, al);

    float di = rsqrtf((float)(dc + 1));
    float4 bm = *reinterpret_cast<const float4*>(bmu + j * 4);
    float4 bl = *reinterpret_cast<const float4*>(bls + j * 4);
    float4 nz = *reinterpret_cast<const float4*>(noise + (size_t)node * DOUT + j * 4);
    float z0 = fmaf(di, am[0], bm.x) + nz.x * expf(fmaf(di, al[0], bl.x));
    float z1 = fmaf(di, am[1], bm.y) + nz.y * expf(fmaf(di, al[1], bl.y));
    float z2 = fmaf(di, am[2], bm.z) + nz.z * expf(fmaf(di, al[2], bl.z));
    float z3 = fmaf(di, am[3], bm.w) + nz.w * expf(fmaf(di, al[3], bl.w));
    uint2 o;
    o.x = f2h2(z0, z1);
    o.y = f2h2(z2, z3);
    *reinterpret_cast<uint2*>(z + (size_t)node * DOUT + j * 4) = o;
}

// ---------------------------------------------------------------------------
// out[e] = sigmoid(dot(z[src[e]], z[dst[e]])), 4 lanes/edge (8 fp16 each)
__global__ void edge_dot(const __half* __restrict__ z, const int* __restrict__ src,
                         const int* __restrict__ dst, float* __restrict__ out, int E) {
    int t = blockIdx.x * blockDim.x + threadIdx.x;
    int e = t >> 2, q = t & 3;
    if (e >= E) return;
    uint4 a = *reinterpret_cast<const uint4*>(z + (size_t)src[e] * DOUT + q * 8);
    uint4 b = *reinterpret_cast<const uint4*>(z + (size_t)dst[e] * DOUT + q * 8);
    float s = 0.f;
    float2 x, y;
    x = h2f2(a.x); y = h2f2(b.x); s += x.x * y.x + x.y * y.y;
    x = h2f2(a.y); y = h2f2(b.y); s += x.x * y.x + x.y * y.y;
    x = h2f2(a.z); y = h2f2(b.z); s += x.x * y.x + x.y * y.y;
    x = h2f2(a.w); y = h2f2(b.w); s += x.x * y.x + x.y * y.y;
    s += __shfl_xor(s, 1);
    s += __shfl_xor(s, 2);
    if (q == 0) out[e] = 1.0f / (1.0f + expf(-s));
}

// ---------------------------------------------------------------------------
extern "C" void kernel_launch(void* const* d_in, const int* in_sizes, int n_in,
                              void* d_out, int out_size, void* d_ws, size_t ws_size,
                              hipStream_t stream) {
    const int*   feat_idx = (const int*)d_in[0];
    const int*   edges    = (const int*)d_in[2];
    const float* table    = (const float*)d_in[3];
    const float* W1       = (const float*)d_in[4];
    const float* b1       = (const float*)d_in[5];
    const float* Wmu      = (const float*)d_in[6];
    const float* bmu      = (const float*)d_in[7];
    const float* Wls      = (const float*)d_in[8];
    const float* bls      = (const float*)d_in[9];
    const float* noise    = (const float*)d_in[10];

    const int N = in_sizes[10] / DOUT;
    const int E = in_sizes[2] / 2;
    const int V = in_sizes[3] / DEMB;

    const int* src = edges;
    const int* dst = edges + E;

    // --- workspace partition ---
    char* ws = (char*)d_ws;
    size_t off = 0;
    auto alloc = [&](size_t bytes) { char* p = ws + off; off += (bytes + 255) & ~size_t(255); return p; };
    u16*    tableW = (u16*)   alloc((size_t)V * DHID * 2);   //  6.4 MB (gathered)
    u16*    h0     = (u16*)   alloc((size_t)N * DHID * 2);   // 12.8 MB (gathered)
    u16*    hcat   = (u16*)   alloc((size_t)N * DHID * 2);   // 12.8 MB (gathered, interleaved)
    __half* zbuf   = (__half*)alloc((size_t)N * DOUT * 2);   //  6.4 MB (gathered)
    int*    adj    = (int*)   alloc((size_t)N * CAP * 4);    // 25.6 MB padded adjacency
    int*    degc   = (int*)   alloc((size_t)N * 4);
    (void)ws_size;

    hipMemsetAsync(degc, 0, (size_t)N * 4, stream);

    const int B = 256;
    const int nbb = (E + B - 1) / B;            // build blocks
    const int nbg = (V + 3) / 4;                // gemm blocks (4 rows each)
    const int ngrp = (nbb > (nbg + 1) / 2) ? nbb : (nbg + 1) / 2;

    // adjacency build ∥ table GEMM (co-dispatched, LDS-free)
    fusedA<<<3 * ngrp, B, 0, stream>>>(src, dst, E, degc, adj, table, W1, tableW, V);

    // h0s = dinv * embedding_bag_mean(tableW, idx)
    {
        long long t = (long long)N * 8;
        emb_bag<<<(unsigned)((t + B - 1) / B), B, 0, stream>>>(feat_idx, tableW, degc, h0, N);
    }

    // conv1 (gather, relu) + gemm_h fused -> interleaved bf16 hcat
    conv1mm<<<(N + 31) / 32, B, 0, stream>>>(h0, degc, adj, b1, Wmu, Wls, hcat, N);

    // conv2 (gather, fused reparameterize) -> fp16 z
    {
        long long t = (long long)N * 8;
        gather_conv2<<<(unsigned)((t + B - 1) / B), B, 0, stream>>>(hcat, degc, adj,
                                                                    bmu, bls, noise, zbuf, N);
    }

    // decoder
    {
        long long t = (long long)E * 4;
        edge_dot<<<(unsigned)((t + B - 1) / B), B, 0, stream>>>(zbuf, src, dst, (float*)d_out, E);
    }
}